// Round 1
// baseline (1099.425 us; speedup 1.0000x reference)
//
#include <hip/hip_runtime.h>
#include <math.h>

#define LRELU_SLOPE 0.01f
#define BN_EPS 1e-5f

static inline int ceil_div(int a, int b) { return (a + b - 1) / b; }

// ---------------- init: deg=1 (self loop), zero counters/sums ----------------
__global__ void k_init(float* __restrict__ deg, int* __restrict__ cnt, int* __restrict__ fill,
                       float* __restrict__ sums, int* __restrict__ gcnt, int N, int G) {
  int i = blockIdx.x * blockDim.x + threadIdx.x;
  if (i < N) { deg[i] = 1.0f; cnt[i] = 0; fill[i] = 0; }
  if (i < 256) sums[i] = 0.0f;
  if (i < G) gcnt[i] = 0;
}

// ---------------- degree + per-dst edge count ----------------
__global__ void k_edge_count(const int* __restrict__ ei, const float* __restrict__ w,
                             float* __restrict__ deg, int* __restrict__ cnt, int E) {
  int e = blockIdx.x * blockDim.x + threadIdx.x;
  if (e >= E) return;
  int d = ei[E + e];            // dst row of edge_index
  atomicAdd(&cnt[d], 1);
  atomicAdd(&deg[d], w[e]);
}

// ---------------- 2-level exclusive scan (N up to 256*1024) ----------------
__global__ void k_scan1(const int* __restrict__ in, int* __restrict__ out,
                        int* __restrict__ bsum, int n) {
  __shared__ int lds[256];
  const int t = threadIdx.x;
  const int base = blockIdx.x * 1024 + t * 4;
  int v0 = 0, v1 = 0, v2 = 0, v3 = 0;
  if (base + 0 < n) v0 = in[base + 0];
  if (base + 1 < n) v1 = in[base + 1];
  if (base + 2 < n) v2 = in[base + 2];
  if (base + 3 < n) v3 = in[base + 3];
  int s = v0 + v1 + v2 + v3;
  lds[t] = s;
  __syncthreads();
#pragma unroll
  for (int off = 1; off < 256; off <<= 1) {
    int y = 0;
    if (t >= off) y = lds[t - off];
    __syncthreads();
    if (t >= off) lds[t] += y;
    __syncthreads();
  }
  int incl = lds[t];
  int excl = incl - s;
  if (base + 0 < n) out[base + 0] = excl;
  if (base + 1 < n) out[base + 1] = excl + v0;
  if (base + 2 < n) out[base + 2] = excl + v0 + v1;
  if (base + 3 < n) out[base + 3] = excl + v0 + v1 + v2;
  if (t == 255) bsum[blockIdx.x] = incl;
}

__global__ void k_scan2(int* __restrict__ bsum, int nb) {  // in-place exclusive, nb<=256
  __shared__ int lds[256];
  int t = threadIdx.x;
  int v = (t < nb) ? bsum[t] : 0;
  lds[t] = v;
  __syncthreads();
#pragma unroll
  for (int off = 1; off < 256; off <<= 1) {
    int y = 0;
    if (t >= off) y = lds[t - off];
    __syncthreads();
    if (t >= off) lds[t] += y;
    __syncthreads();
  }
  if (t < nb) bsum[t] = lds[t] - v;
}

__global__ void k_scan3(int* __restrict__ rowstart, const int* __restrict__ bscan,
                        const float* __restrict__ deg, float* __restrict__ dinv, int N, int E) {
  int i = blockIdx.x * blockDim.x + threadIdx.x;
  if (i < N) {
    rowstart[i] += bscan[i >> 10];
    float d = deg[i];
    dinv[i] = (d > 0.0f) ? rsqrtf(d) : 0.0f;
  }
  if (i == N) rowstart[N] = E;
}

// ---------------- CSR fill: col[p]=src, val[p]=w*dinv[src] ----------------
__global__ void k_fill(const int* __restrict__ ei, const float* __restrict__ w,
                       const int* __restrict__ rowstart, int* __restrict__ fill,
                       const float* __restrict__ dinv, int* __restrict__ col,
                       float* __restrict__ val, int E) {
  int e = blockIdx.x * blockDim.x + threadIdx.x;
  if (e >= E) return;
  int s = ei[e];
  int d = ei[E + e];
  int p = rowstart[d] + atomicAdd(&fill[d], 1);
  col[p] = s;
  val[p] = w[e] * dinv[s];
}

// ---------------- GEMM: H[N,64] = X[N,K] @ W[K,64]  (fp32, VALU) ----------------
// Block: 256 threads = 256 node rows; x tile transpose-free staged in LDS (stride 33,
// conflict-free inner reads); W rows fetched with uniform (scalar) loads.
template <int K>
__launch_bounds__(256)
__global__ void k_gemm(const float* __restrict__ X, const float* __restrict__ W,
                       float* __restrict__ H, int N) {
  __shared__ float xl[256 * 33];
  const int t = threadIdx.x;
  const int node = blockIdx.x * 256 + t;
  float acc[64];
#pragma unroll
  for (int j = 0; j < 64; ++j) acc[j] = 0.0f;

  for (int kt = 0; kt < K; kt += 32) {
    __syncthreads();  // protect previous tile reads
#pragma unroll
    for (int l = 0; l < 8; ++l) {
      int row = (t >> 3) + l * 32;
      int kc = (t & 7) * 4;
      int gn = blockIdx.x * 256 + row;
      float4 v = make_float4(0.f, 0.f, 0.f, 0.f);
      if (gn < N) v = *(const float4*)(X + (size_t)gn * K + kt + kc);
      float* p = &xl[row * 33 + kc];
      p[0] = v.x; p[1] = v.y; p[2] = v.z; p[3] = v.w;
    }
    __syncthreads();
#pragma unroll 4
    for (int k = 0; k < 32; ++k) {
      float xv = xl[t * 33 + k];
      const float4* Wr = (const float4*)(W + (size_t)(kt + k) * 64);
#pragma unroll
      for (int j4 = 0; j4 < 16; ++j4) {
        float4 wv = Wr[j4];
        acc[4 * j4 + 0] += xv * wv.x;
        acc[4 * j4 + 1] += xv * wv.y;
        acc[4 * j4 + 2] += xv * wv.z;
        acc[4 * j4 + 3] += xv * wv.w;
      }
    }
  }
  if (node < N) {
#pragma unroll
    for (int j4 = 0; j4 < 16; ++j4) {
      float4 o = make_float4(acc[4 * j4 + 0], acc[4 * j4 + 1], acc[4 * j4 + 2], acc[4 * j4 + 3]);
      *(float4*)(H + (size_t)node * 64 + 4 * j4) = o;
    }
  }
}

// ---------------- CSR aggregation: out[d] = dinv[d]*sum(val*h[src]) + dinv[d]^2*h[d] + b ----
// 16 lanes per node (float4 each = 64 features), 16 nodes per 256-thread block.
__launch_bounds__(256)
__global__ void k_agg(const float* __restrict__ hin, float* __restrict__ hout,
                      const float* __restrict__ bias, const float* __restrict__ dinv,
                      const int* __restrict__ rowstart, const int* __restrict__ col,
                      const float* __restrict__ val, int N, int apply_lrelu) {
  const int t = threadIdx.x;
  const int grp = t >> 4;
  const int lane = t & 15;
  const int d = blockIdx.x * 16 + grp;
  if (d >= N) return;
  const int r0 = rowstart[d];
  const int r1 = rowstart[d + 1];
  float4 acc = make_float4(0.f, 0.f, 0.f, 0.f);
  for (int r = r0; r < r1; ++r) {
    int s = col[r];
    float v = val[r];
    float4 hv = *(const float4*)(hin + (size_t)s * 64 + lane * 4);
    acc.x += v * hv.x;
    acc.y += v * hv.y;
    acc.z += v * hv.z;
    acc.w += v * hv.w;
  }
  float di = dinv[d];
  float di2 = di * di;
  float4 hd = *(const float4*)(hin + (size_t)d * 64 + lane * 4);
  float4 b4 = *(const float4*)(bias + lane * 4);
  float4 o;
  o.x = di * acc.x + di2 * hd.x + b4.x;
  o.y = di * acc.y + di2 * hd.y + b4.y;
  o.z = di * acc.z + di2 * hd.z + b4.z;
  o.w = di * acc.w + di2 * hd.w + b4.w;
  if (apply_lrelu) {
    o.x = (o.x > 0.f) ? o.x : LRELU_SLOPE * o.x;
    o.y = (o.y > 0.f) ? o.y : LRELU_SLOPE * o.y;
    o.z = (o.z > 0.f) ? o.z : LRELU_SLOPE * o.z;
    o.w = (o.w > 0.f) ? o.w : LRELU_SLOPE * o.w;
  }
  *(float4*)(hout + (size_t)d * 64 + lane * 4) = o;
}

// ---------------- BN column stats: s[c] = sum h[:,c], ss[c] = sum h[:,c]^2 ----------------
__launch_bounds__(256)
__global__ void k_stats(const float* __restrict__ h, float* __restrict__ s,
                        float* __restrict__ ss, int N) {
  __shared__ float ls[256], lss[256];
  const int t = threadIdx.x;
  const int c = t & 63;
  float a = 0.f, a2 = 0.f;
  for (int n = blockIdx.x * 4 + (t >> 6); n < N; n += gridDim.x * 4) {
    float v = h[(size_t)n * 64 + c];
    a += v;
    a2 += v * v;
  }
  ls[t] = a;
  lss[t] = a2;
  __syncthreads();
  if (t < 64) {
    a = ls[t] + ls[t + 64] + ls[t + 128] + ls[t + 192];
    a2 = lss[t] + lss[t + 64] + lss[t + 128] + lss[t + 192];
    atomicAdd(&s[c], a);
    atomicAdd(&ss[c], a2);
  }
}

// ---------------- BN apply + LeakyReLU ----------------
__launch_bounds__(256)
__global__ void k_bnapply(const float* __restrict__ hin, float* __restrict__ hout,
                          const float* __restrict__ s, const float* __restrict__ ss,
                          const float* __restrict__ g, const float* __restrict__ be,
                          int N) {
  int i = blockIdx.x * blockDim.x + threadIdx.x;  // index over N*16 float4s
  if (i >= N * 16) return;
  int c0 = (i & 15) * 4;
  float invN = 1.0f / (float)N;
  float4 v = ((const float4*)hin)[i];
  float o[4] = {v.x, v.y, v.z, v.w};
#pragma unroll
  for (int k = 0; k < 4; ++k) {
    int c = c0 + k;
    float mean = s[c] * invN;
    float var = ss[c] * invN - mean * mean;
    float scale = g[c] * rsqrtf(var + BN_EPS);
    float r = (o[k] - mean) * scale + be[c];
    o[k] = (r > 0.f) ? r : LRELU_SLOPE * r;
  }
  ((float4*)hout)[i] = make_float4(o[0], o[1], o[2], o[3]);
}

// ---------------- graph node counts + offsets ----------------
__global__ void k_gcount(const int* __restrict__ batch, int* __restrict__ gcnt, int N) {
  int i = blockIdx.x * blockDim.x + threadIdx.x;
  if (i < N) atomicAdd(&gcnt[batch[i]], 1);
}

__global__ void k_gscan(const int* __restrict__ gcnt, int* __restrict__ gstart, int G, int N) {
  __shared__ int lds[256];
  int t = threadIdx.x;
  int v = (t < G) ? gcnt[t] : 0;
  lds[t] = v;
  __syncthreads();
#pragma unroll
  for (int off = 1; off < 256; off <<= 1) {
    int y = 0;
    if (t >= off) y = lds[t - off];
    __syncthreads();
    if (t >= off) lds[t] += y;
    __syncthreads();
  }
  if (t < G) gstart[t] = lds[t] - v;
  if (t == 0) gstart[G] = N;
}

// ---------------- pooling (max & mean per graph) + FC, fused ----------------
__launch_bounds__(256)
__global__ void k_pool(const float* __restrict__ h, const int* __restrict__ gstart,
                       const float* __restrict__ Wfc, const float* __restrict__ bfc,
                       float* __restrict__ out, int G) {
  __shared__ float lmx[256], lsm[256], red[128];
  const int g = blockIdx.x;
  const int t = threadIdx.x;
  const int c = t & 63;
  const int sub = t >> 6;
  const int n0 = gstart[g];
  const int n1 = gstart[g + 1];
  float mx = -INFINITY, sm = 0.f;
  for (int n = n0 + sub; n < n1; n += 4) {
    float v = h[(size_t)n * 64 + c];
    mx = fmaxf(mx, v);
    sm += v;
  }
  lmx[t] = mx;
  lsm[t] = sm;
  __syncthreads();
  if (t < 64) {
    mx = fmaxf(fmaxf(lmx[t], lmx[t + 64]), fmaxf(lmx[t + 128], lmx[t + 192]));
    sm = lsm[t] + lsm[t + 64] + lsm[t + 128] + lsm[t + 192];
    float cntf = (float)(n1 - n0);
    float mean = sm / fmaxf(cntf, 1.0f);
    red[t] = mx * Wfc[t];
    red[t + 64] = mean * Wfc[64 + t];
  }
  __syncthreads();
  for (int st = 64; st >= 1; st >>= 1) {
    if (t < st) red[t] += red[t + st];
    __syncthreads();
  }
  if (t == 0) out[g] = red[0] + bfc[0];
}

// ---------------- host launch ----------------
extern "C" void kernel_launch(void* const* d_in, const int* in_sizes, int n_in,
                              void* d_out, int out_size, void* d_ws, size_t ws_size,
                              hipStream_t stream) {
  const float* x = (const float*)d_in[0];
  const int* ei = (const int*)d_in[1];
  const int* batch = (const int*)d_in[2];
  const float* eattr = (const float*)d_in[3];
  const float* W0 = (const float*)d_in[4];
  const float* b0 = (const float*)d_in[5];
  const float* g0 = (const float*)d_in[6];
  const float* be0 = (const float*)d_in[7];
  const float* W1 = (const float*)d_in[8];
  const float* b1 = (const float*)d_in[9];
  const float* g1 = (const float*)d_in[10];
  const float* be1 = (const float*)d_in[11];
  const float* W2 = (const float*)d_in[12];
  const float* b2 = (const float*)d_in[13];
  const float* W3 = (const float*)d_in[14];
  const float* b3 = (const float*)d_in[15];
  const float* Wfc = (const float*)d_in[16];
  const float* bfc = (const float*)d_in[17];
  float* out = (float*)d_out;

  const int N = in_sizes[2];       // batch is [N]
  const int E = in_sizes[3];       // edge_attr is [E]
  const int CIN = in_sizes[0] / N; // 128
  const int G = out_size;          // [G,1]

  // workspace carve-up (256B-aligned slices)
  size_t off = 0;
  auto alloc = [&](size_t bytes) -> void* {
    void* p = (char*)d_ws + off;
    off += (bytes + 255) & ~(size_t)255;
    return p;
  };
  float* deg = (float*)alloc((size_t)N * 4);
  float* dinv = (float*)alloc((size_t)N * 4);
  int* cnt = (int*)alloc((size_t)N * 4);
  int* rowstart = (int*)alloc((size_t)(N + 1) * 4);
  int* fill = (int*)alloc((size_t)N * 4);
  int* bsum = (int*)alloc(1024 * 4);
  int* col = (int*)alloc((size_t)E * 4);
  float* val = (float*)alloc((size_t)E * 4);
  float* A = (float*)alloc((size_t)N * 64 * 4);
  float* B = (float*)alloc((size_t)N * 64 * 4);
  float* sums = (float*)alloc(256 * 4);  // s0|ss0|s1|ss1
  int* gcnt = (int*)alloc((size_t)G * 4);
  int* gstart = (int*)alloc((size_t)(G + 1) * 4);
  (void)ws_size; (void)n_in; (void)CIN;

  const int nb = ceil_div(N, 1024);

  // graph structure (layer-invariant)
  k_init<<<ceil_div(N, 256), 256, 0, stream>>>(deg, cnt, fill, sums, gcnt, N, G);
  k_edge_count<<<ceil_div(E, 256), 256, 0, stream>>>(ei, eattr, deg, cnt, E);
  k_scan1<<<nb, 256, 0, stream>>>(cnt, rowstart, bsum, N);
  k_scan2<<<1, 256, 0, stream>>>(bsum, nb);
  k_scan3<<<ceil_div(N + 1, 256), 256, 0, stream>>>(rowstart, bsum, deg, dinv, N, E);
  k_fill<<<ceil_div(E, 256), 256, 0, stream>>>(ei, eattr, rowstart, fill, dinv, col, val, E);
  k_gcount<<<ceil_div(N, 256), 256, 0, stream>>>(batch, gcnt, N);
  k_gscan<<<1, 256, 0, stream>>>(gcnt, gstart, G, N);

  // layer 0: gemm(x,W0)->A; agg A->B; stats(B); bn+lrelu B->A
  k_gemm<128><<<ceil_div(N, 256), 256, 0, stream>>>(x, W0, A, N);
  k_agg<<<ceil_div(N, 16), 256, 0, stream>>>(A, B, b0, dinv, rowstart, col, val, N, 0);
  k_stats<<<256, 256, 0, stream>>>(B, sums + 0, sums + 64, N);
  k_bnapply<<<ceil_div(N * 16, 256), 256, 0, stream>>>(B, A, sums + 0, sums + 64, g0, be0, N);

  // layer 1: gemm(A,W1)->B; agg B->A; stats(A); bn+lrelu A->B
  k_gemm<64><<<ceil_div(N, 256), 256, 0, stream>>>(A, W1, B, N);
  k_agg<<<ceil_div(N, 16), 256, 0, stream>>>(B, A, b1, dinv, rowstart, col, val, N, 0);
  k_stats<<<256, 256, 0, stream>>>(A, sums + 128, sums + 192, N);
  k_bnapply<<<ceil_div(N * 16, 256), 256, 0, stream>>>(A, B, sums + 128, sums + 192, g1, be1, N);

  // layer 2: gemm(B,W2)->A; agg(+lrelu) A->B
  k_gemm<64><<<ceil_div(N, 256), 256, 0, stream>>>(B, W2, A, N);
  k_agg<<<ceil_div(N, 16), 256, 0, stream>>>(A, B, b2, dinv, rowstart, col, val, N, 1);

  // layer 3: gemm(B,W3)->A; agg(+lrelu) A->B
  k_gemm<64><<<ceil_div(N, 256), 256, 0, stream>>>(B, W3, A, N);
  k_agg<<<ceil_div(N, 16), 256, 0, stream>>>(A, B, b3, dinv, rowstart, col, val, N, 1);

  // pooling + FC
  k_pool<<<G, 256, 0, stream>>>(B, gstart, Wfc, bfc, out, G);
}

// Round 2
// 966.407 us; speedup vs baseline: 1.1376x; 1.1376x over previous
//
#include <hip/hip_runtime.h>
#include <math.h>

#define LRELU_SLOPE 0.01f
#define BN_EPS 1e-5f

static inline int ceil_div(int a, int b) { return (a + b - 1) / b; }

// ---------------- init: deg=1 (self loop), zero counters/sums ----------------
__global__ void k_init(float* __restrict__ deg, int* __restrict__ cnt, int* __restrict__ fill,
                       float* __restrict__ sums, int N) {
  int i = blockIdx.x * blockDim.x + threadIdx.x;
  if (i < N) { deg[i] = 1.0f; cnt[i] = 0; fill[i] = 0; }
  if (i < 256) sums[i] = 0.0f;
}

// ---------------- degree + per-dst edge count ----------------
__global__ void k_edge_count(const int* __restrict__ ei, const float* __restrict__ w,
                             float* __restrict__ deg, int* __restrict__ cnt, int E) {
  int e = blockIdx.x * blockDim.x + threadIdx.x;
  if (e >= E) return;
  int d = ei[E + e];            // dst row of edge_index
  atomicAdd(&cnt[d], 1);
  atomicAdd(&deg[d], w[e]);
}

// ---------------- 2-level exclusive scan (N up to 256*1024) ----------------
__global__ void k_scan1(const int* __restrict__ in, int* __restrict__ out,
                        int* __restrict__ bsum, int n) {
  __shared__ int lds[256];
  const int t = threadIdx.x;
  const int base = blockIdx.x * 1024 + t * 4;
  int v0 = 0, v1 = 0, v2 = 0, v3 = 0;
  if (base + 0 < n) v0 = in[base + 0];
  if (base + 1 < n) v1 = in[base + 1];
  if (base + 2 < n) v2 = in[base + 2];
  if (base + 3 < n) v3 = in[base + 3];
  int s = v0 + v1 + v2 + v3;
  lds[t] = s;
  __syncthreads();
#pragma unroll
  for (int off = 1; off < 256; off <<= 1) {
    int y = 0;
    if (t >= off) y = lds[t - off];
    __syncthreads();
    if (t >= off) lds[t] += y;
    __syncthreads();
  }
  int incl = lds[t];
  int excl = incl - s;
  if (base + 0 < n) out[base + 0] = excl;
  if (base + 1 < n) out[base + 1] = excl + v0;
  if (base + 2 < n) out[base + 2] = excl + v0 + v1;
  if (base + 3 < n) out[base + 3] = excl + v0 + v1 + v2;
  if (t == 255) bsum[blockIdx.x] = incl;
}

__global__ void k_scan2(int* __restrict__ bsum, int nb) {  // in-place exclusive, nb<=256
  __shared__ int lds[256];
  int t = threadIdx.x;
  int v = (t < nb) ? bsum[t] : 0;
  lds[t] = v;
  __syncthreads();
#pragma unroll
  for (int off = 1; off < 256; off <<= 1) {
    int y = 0;
    if (t >= off) y = lds[t - off];
    __syncthreads();
    if (t >= off) lds[t] += y;
    __syncthreads();
  }
  if (t < nb) bsum[t] = lds[t] - v;
}

__global__ void k_scan3(int* __restrict__ rowstart, const int* __restrict__ bscan,
                        const float* __restrict__ deg, float* __restrict__ dinv, int N, int E) {
  int i = blockIdx.x * blockDim.x + threadIdx.x;
  if (i < N) {
    rowstart[i] += bscan[i >> 10];
    float d = deg[i];
    dinv[i] = (d > 0.0f) ? rsqrtf(d) : 0.0f;
  }
  if (i == N) rowstart[N] = E;
}

// ---------------- CSR fill: col[p]=src, val[p]=w*dinv[src] ----------------
__global__ void k_fill(const int* __restrict__ ei, const float* __restrict__ w,
                       const int* __restrict__ rowstart, int* __restrict__ fill,
                       const float* __restrict__ dinv, int* __restrict__ col,
                       float* __restrict__ val, int E) {
  int e = blockIdx.x * blockDim.x + threadIdx.x;
  if (e >= E) return;
  int s = ei[e];
  int d = ei[E + e];
  int p = rowstart[d] + atomicAdd(&fill[d], 1);
  col[p] = s;
  val[p] = w[e] * dinv[s];
}

// ---------------- GEMM: H[N,64] = X[N,K] @ W[K,64]  (fp32, VALU) ----------------
template <int K>
__launch_bounds__(256)
__global__ void k_gemm(const float* __restrict__ X, const float* __restrict__ W,
                       float* __restrict__ H, int N) {
  __shared__ float xl[256 * 33];
  const int t = threadIdx.x;
  const int node = blockIdx.x * 256 + t;
  float acc[64];
#pragma unroll
  for (int j = 0; j < 64; ++j) acc[j] = 0.0f;

  for (int kt = 0; kt < K; kt += 32) {
    __syncthreads();  // protect previous tile reads
#pragma unroll
    for (int l = 0; l < 8; ++l) {
      int row = (t >> 3) + l * 32;
      int kc = (t & 7) * 4;
      int gn = blockIdx.x * 256 + row;
      float4 v = make_float4(0.f, 0.f, 0.f, 0.f);
      if (gn < N) v = *(const float4*)(X + (size_t)gn * K + kt + kc);
      float* p = &xl[row * 33 + kc];
      p[0] = v.x; p[1] = v.y; p[2] = v.z; p[3] = v.w;
    }
    __syncthreads();
#pragma unroll 4
    for (int k = 0; k < 32; ++k) {
      float xv = xl[t * 33 + k];
      const float4* Wr = (const float4*)(W + (size_t)(kt + k) * 64);
#pragma unroll
      for (int j4 = 0; j4 < 16; ++j4) {
        float4 wv = Wr[j4];
        acc[4 * j4 + 0] += xv * wv.x;
        acc[4 * j4 + 1] += xv * wv.y;
        acc[4 * j4 + 2] += xv * wv.z;
        acc[4 * j4 + 3] += xv * wv.w;
      }
    }
  }
  if (node < N) {
#pragma unroll
    for (int j4 = 0; j4 < 16; ++j4) {
      float4 o = make_float4(acc[4 * j4 + 0], acc[4 * j4 + 1], acc[4 * j4 + 2], acc[4 * j4 + 3]);
      *(float4*)(H + (size_t)node * 64 + 4 * j4) = o;
    }
  }
}

// ---------------- CSR aggregation: out[d] = dinv[d]*sum(val*h[src]) + dinv[d]^2*h[d] + b ----
__launch_bounds__(256)
__global__ void k_agg(const float* __restrict__ hin, float* __restrict__ hout,
                      const float* __restrict__ bias, const float* __restrict__ dinv,
                      const int* __restrict__ rowstart, const int* __restrict__ col,
                      const float* __restrict__ val, int N, int apply_lrelu) {
  const int t = threadIdx.x;
  const int grp = t >> 4;
  const int lane = t & 15;
  const int d = blockIdx.x * 16 + grp;
  if (d >= N) return;
  const int r0 = rowstart[d];
  const int r1 = rowstart[d + 1];
  float4 acc = make_float4(0.f, 0.f, 0.f, 0.f);
  for (int r = r0; r < r1; ++r) {
    int s = col[r];
    float v = val[r];
    float4 hv = *(const float4*)(hin + (size_t)s * 64 + lane * 4);
    acc.x += v * hv.x;
    acc.y += v * hv.y;
    acc.z += v * hv.z;
    acc.w += v * hv.w;
  }
  float di = dinv[d];
  float di2 = di * di;
  float4 hd = *(const float4*)(hin + (size_t)d * 64 + lane * 4);
  float4 b4 = *(const float4*)(bias + lane * 4);
  float4 o;
  o.x = di * acc.x + di2 * hd.x + b4.x;
  o.y = di * acc.y + di2 * hd.y + b4.y;
  o.z = di * acc.z + di2 * hd.z + b4.z;
  o.w = di * acc.w + di2 * hd.w + b4.w;
  if (apply_lrelu) {
    o.x = (o.x > 0.f) ? o.x : LRELU_SLOPE * o.x;
    o.y = (o.y > 0.f) ? o.y : LRELU_SLOPE * o.y;
    o.z = (o.z > 0.f) ? o.z : LRELU_SLOPE * o.z;
    o.w = (o.w > 0.f) ? o.w : LRELU_SLOPE * o.w;
  }
  *(float4*)(hout + (size_t)d * 64 + lane * 4) = o;
}

// ---------------- BN column stats ----------------
__launch_bounds__(256)
__global__ void k_stats(const float* __restrict__ h, float* __restrict__ s,
                        float* __restrict__ ss, int N) {
  __shared__ float ls[256], lss[256];
  const int t = threadIdx.x;
  const int c = t & 63;
  float a = 0.f, a2 = 0.f;
  for (int n = blockIdx.x * 4 + (t >> 6); n < N; n += gridDim.x * 4) {
    float v = h[(size_t)n * 64 + c];
    a += v;
    a2 += v * v;
  }
  ls[t] = a;
  lss[t] = a2;
  __syncthreads();
  if (t < 64) {
    a = ls[t] + ls[t + 64] + ls[t + 128] + ls[t + 192];
    a2 = lss[t] + lss[t + 64] + lss[t + 128] + lss[t + 192];
    atomicAdd(&s[c], a);
    atomicAdd(&ss[c], a2);
  }
}

// ---------------- BN apply + LeakyReLU ----------------
__launch_bounds__(256)
__global__ void k_bnapply(const float* __restrict__ hin, float* __restrict__ hout,
                          const float* __restrict__ s, const float* __restrict__ ss,
                          const float* __restrict__ g, const float* __restrict__ be,
                          int N) {
  int i = blockIdx.x * blockDim.x + threadIdx.x;  // index over N*16 float4s
  if (i >= N * 16) return;
  int c0 = (i & 15) * 4;
  float invN = 1.0f / (float)N;
  float4 v = ((const float4*)hin)[i];
  float o[4] = {v.x, v.y, v.z, v.w};
#pragma unroll
  for (int k = 0; k < 4; ++k) {
    int c = c0 + k;
    float mean = s[c] * invN;
    float var = ss[c] * invN - mean * mean;
    float scale = g[c] * rsqrtf(var + BN_EPS);
    float r = (o[k] - mean) * scale + be[c];
    o[k] = (r > 0.f) ? r : LRELU_SLOPE * r;
  }
  ((float4*)hout)[i] = make_float4(o[0], o[1], o[2], o[3]);
}

// ---------------- graph boundaries from sorted batch (atomic-free) ----------------
// gstart[g] = first node index with batch >= g; gstart[G] = N.
__global__ void k_gbounds(const int* __restrict__ batch, int* __restrict__ gstart,
                          int N, int G) {
  int i = blockIdx.x * blockDim.x + threadIdx.x;
  if (i >= N) return;
  int b = batch[i];
  int prev = (i == 0) ? -1 : batch[i - 1];
  for (int g = prev + 1; g <= b; ++g) gstart[g] = i;   // batch sorted => prev <= b
  if (i == N - 1) {
    for (int g = b + 1; g <= G; ++g) gstart[g] = N;
  }
}

// ---------------- pooling (max & mean per graph) + FC, fused ----------------
__launch_bounds__(256)
__global__ void k_pool(const float* __restrict__ h, const int* __restrict__ gstart,
                       const float* __restrict__ Wfc, const float* __restrict__ bfc,
                       float* __restrict__ out, int G) {
  __shared__ float lmx[256], lsm[256], red[128];
  const int g = blockIdx.x;
  const int t = threadIdx.x;
  const int c = t & 63;
  const int sub = t >> 6;
  const int n0 = gstart[g];
  const int n1 = gstart[g + 1];
  float mx = -INFINITY, sm = 0.f;
  for (int n = n0 + sub; n < n1; n += 4) {
    float v = h[(size_t)n * 64 + c];
    mx = fmaxf(mx, v);
    sm += v;
  }
  lmx[t] = mx;
  lsm[t] = sm;
  __syncthreads();
  if (t < 64) {
    mx = fmaxf(fmaxf(lmx[t], lmx[t + 64]), fmaxf(lmx[t + 128], lmx[t + 192]));
    sm = lsm[t] + lsm[t + 64] + lsm[t + 128] + lsm[t + 192];
    float cntf = (float)(n1 - n0);
    float mean = sm / fmaxf(cntf, 1.0f);
    red[t] = mx * Wfc[t];
    red[t + 64] = mean * Wfc[64 + t];
  }
  __syncthreads();
  for (int st = 64; st >= 1; st >>= 1) {
    if (t < st) red[t] += red[t + st];
    __syncthreads();
  }
  if (t == 0) out[g] = red[0] + bfc[0];
}

// ---------------- host launch ----------------
extern "C" void kernel_launch(void* const* d_in, const int* in_sizes, int n_in,
                              void* d_out, int out_size, void* d_ws, size_t ws_size,
                              hipStream_t stream) {
  const float* x = (const float*)d_in[0];
  const int* ei = (const int*)d_in[1];
  const int* batch = (const int*)d_in[2];
  const float* eattr = (const float*)d_in[3];
  const float* W0 = (const float*)d_in[4];
  const float* b0 = (const float*)d_in[5];
  const float* g0 = (const float*)d_in[6];
  const float* be0 = (const float*)d_in[7];
  const float* W1 = (const float*)d_in[8];
  const float* b1 = (const float*)d_in[9];
  const float* g1 = (const float*)d_in[10];
  const float* be1 = (const float*)d_in[11];
  const float* W2 = (const float*)d_in[12];
  const float* b2 = (const float*)d_in[13];
  const float* W3 = (const float*)d_in[14];
  const float* b3 = (const float*)d_in[15];
  const float* Wfc = (const float*)d_in[16];
  const float* bfc = (const float*)d_in[17];
  float* out = (float*)d_out;

  const int N = in_sizes[2];       // batch is [N]
  const int E = in_sizes[3];       // edge_attr is [E]
  const int CIN = in_sizes[0] / N; // 128
  const int G = out_size;          // [G,1]

  // workspace carve-up (256B-aligned slices)
  size_t off = 0;
  auto alloc = [&](size_t bytes) -> void* {
    void* p = (char*)d_ws + off;
    off += (bytes + 255) & ~(size_t)255;
    return p;
  };
  float* deg = (float*)alloc((size_t)N * 4);
  float* dinv = (float*)alloc((size_t)N * 4);
  int* cnt = (int*)alloc((size_t)N * 4);
  int* rowstart = (int*)alloc((size_t)(N + 1) * 4);
  int* fill = (int*)alloc((size_t)N * 4);
  int* bsum = (int*)alloc(1024 * 4);
  int* col = (int*)alloc((size_t)E * 4);
  float* val = (float*)alloc((size_t)E * 4);
  float* A = (float*)alloc((size_t)N * 64 * 4);
  float* B = (float*)alloc((size_t)N * 64 * 4);
  float* sums = (float*)alloc(256 * 4);  // s0|ss0|s1|ss1
  int* gstart = (int*)alloc((size_t)(G + 1) * 4);
  (void)ws_size; (void)n_in; (void)CIN;

  const int nb = ceil_div(N, 1024);

  // graph structure (layer-invariant)
  k_init<<<ceil_div(N, 256), 256, 0, stream>>>(deg, cnt, fill, sums, N);
  k_edge_count<<<ceil_div(E, 256), 256, 0, stream>>>(ei, eattr, deg, cnt, E);
  k_scan1<<<nb, 256, 0, stream>>>(cnt, rowstart, bsum, N);
  k_scan2<<<1, 256, 0, stream>>>(bsum, nb);
  k_scan3<<<ceil_div(N + 1, 256), 256, 0, stream>>>(rowstart, bsum, deg, dinv, N, E);
  k_fill<<<ceil_div(E, 256), 256, 0, stream>>>(ei, eattr, rowstart, fill, dinv, col, val, E);
  k_gbounds<<<ceil_div(N, 256), 256, 0, stream>>>(batch, gstart, N, G);

  // layer 0: gemm(x,W0)->A; agg A->B; stats(B); bn+lrelu B->A
  k_gemm<128><<<ceil_div(N, 256), 256, 0, stream>>>(x, W0, A, N);
  k_agg<<<ceil_div(N, 16), 256, 0, stream>>>(A, B, b0, dinv, rowstart, col, val, N, 0);
  k_stats<<<256, 256, 0, stream>>>(B, sums + 0, sums + 64, N);
  k_bnapply<<<ceil_div(N * 16, 256), 256, 0, stream>>>(B, A, sums + 0, sums + 64, g0, be0, N);

  // layer 1: gemm(A,W1)->B; agg B->A; stats(A); bn+lrelu A->B
  k_gemm<64><<<ceil_div(N, 256), 256, 0, stream>>>(A, W1, B, N);
  k_agg<<<ceil_div(N, 16), 256, 0, stream>>>(B, A, b1, dinv, rowstart, col, val, N, 0);
  k_stats<<<256, 256, 0, stream>>>(A, sums + 128, sums + 192, N);
  k_bnapply<<<ceil_div(N * 16, 256), 256, 0, stream>>>(A, B, sums + 128, sums + 192, g1, be1, N);

  // layer 2: gemm(B,W2)->A; agg(+lrelu) A->B
  k_gemm<64><<<ceil_div(N, 256), 256, 0, stream>>>(B, W2, A, N);
  k_agg<<<ceil_div(N, 16), 256, 0, stream>>>(A, B, b2, dinv, rowstart, col, val, N, 1);

  // layer 3: gemm(B,W3)->A; agg(+lrelu) A->B
  k_gemm<64><<<ceil_div(N, 256), 256, 0, stream>>>(B, W3, A, N);
  k_agg<<<ceil_div(N, 16), 256, 0, stream>>>(A, B, b3, dinv, rowstart, col, val, N, 1);

  // pooling + FC
  k_pool<<<G, 256, 0, stream>>>(B, gstart, Wfc, bfc, out, G);
}